// Round 8
// baseline (6880.206 us; speedup 1.0000x reference)
//
#include <hip/hip_runtime.h>
#include <hip/hip_fp16.h>
#include <math.h>

#define N 150
#define NP 160            // padded: 4 workers × 40 cols, float4-aligned
#define QUART 40
#define QUADS 10          // QUART/4
#define BLOCK 640         // 10 waves; 4 workers per row (600 active)
#define ITERS 100
#define WARM 5

#define PI_F 3.14159265358979323846f
#define TWO_PI_F 6.28318530717958647692f
#define EPS_F 1e-16f
// SINKHORN_EPS = 0.05 ; base-2 log domain: K = C/(eps*ln2), result scale eps*ln2
#define EPSLN2 0.03465735902799726f
#define INV_EPSLN2 28.853900817779268f
#define NEGBIG -1e30f
#define PADK -60000.0f    // fp16-finite pad: exp2 -> 0, K*0 -> 0 (no inf*0 NaN)

#if __has_builtin(__builtin_amdgcn_exp2f)
#define FEXP2(x) __builtin_amdgcn_exp2f(x)
#else
#define FEXP2(x) exp2f(x)
#endif
#if __has_builtin(__builtin_amdgcn_logf)
#define FLOG2(x) __builtin_amdgcn_logf(x)
#else
#define FLOG2(x) log2f(x)
#endif

// DPP quad_perm cross-lane (workers of one row are a lane-quad): pure VALU.
template <int PAT>
__device__ __forceinline__ float qp_swap(float v) {
    return __int_as_float(__builtin_amdgcn_update_dpp(
        0, __float_as_int(v), PAT, 0xF, 0xF, true));
}
__device__ __forceinline__ float quad_sum(float v) {
    v += qp_swap<0xB1>(v);   // xor 1
    v += qp_swap<0x4E>(v);   // xor 2
    return v;
}
__device__ __forceinline__ float quad_max(float v) {
    v = fmaxf(v, qp_swap<0xB1>(v));
    v = fmaxf(v, qp_swap<0x4E>(v));
    return v;
}

__device__ __forceinline__ float blockReduceSum(float v, float* red) {
    for (int o = 32; o > 0; o >>= 1) v += __shfl_down(v, o, 64);
    const int lane = threadIdx.x & 63;
    const int wv = threadIdx.x >> 6;
    __syncthreads();
    if (lane == 0) red[wv] = v;
    __syncthreads();
    float s = 0.f;
    #pragma unroll
    for (int i = 0; i < BLOCK / 64; ++i) s += red[i];
    return s;
}

__global__ __launch_bounds__(BLOCK, 6) void emd_kernel(
    const float* __restrict__ p_recons,
    const float* __restrict__ p_target,
    float* __restrict__ out)
{
    __shared__ float xeta[N], xphi[N], yeta[N], yphi[N];
    __shared__ float l2a[N], l2b[N];
    __shared__ __align__(16) float uu[NP];
    __shared__ __align__(16) float vv[NP];
    __shared__ float red[BLOCK / 64];

    const int b = blockIdx.x;
    const int tid = threadIdx.x;

    // ---- coordinate transform (both clouds) ----
    for (int c = 0; c < 2; ++c) {
        const float* P = (c == 0 ? p_recons : p_target) + (size_t)b * (N * 3);
        float px = 0.f, py = 0.f, pz = 0.f;
        if (tid < N) {
            px = P[tid * 3 + 0];
            py = P[tid * 3 + 1];
            pz = P[tid * 3 + 2];
        }
        const float jx = blockReduceSum(px, red);
        const float jy = blockReduceSum(py, red);
        const float jz = blockReduceSum(pz, red);
        const float jpt  = sqrtf(jx * jx + jy * jy + EPS_F);
        const float jphi = atan2f(jy + EPS_F, jx + EPS_F);
        const float jeta = asinhf(jz / (jpt + EPS_F));

        float ptrel = 0.f, erel = 0.f, prel = 0.f;
        if (tid < N) {
            const float pt  = sqrtf(px * px + py * py + EPS_F);
            const float phi = atan2f(py + EPS_F, px + EPS_F);
            const float eta = asinhf(pz / (pt + EPS_F));
            erel = eta - jeta;
            float d = phi - jphi + PI_F;
            d = fmodf(d, TWO_PI_F);            // JAX % is floor-mod
            if (d < 0.f) d += TWO_PI_F;
            prel = d - PI_F;
            ptrel = pt / (jpt + EPS_F);
        }
        const float spt = blockReduceSum(ptrel, red);
        if (tid < N) {
            const float aa = ptrel / (spt + EPS_F);
            if (c == 0) { xeta[tid] = erel; xphi[tid] = prel; l2a[tid] = FLOG2(aa + EPS_F); }
            else        { yeta[tid] = erel; yphi[tid] = prel; l2b[tid] = FLOG2(aa + EPS_F); }
        }
    }
    __syncthreads();

    // ---- register-resident PACKED fp16 -K slices: 4 workers/row, 40 cols each ----
    // nKu2[s] = (-K[r][q*40+2s], -K[r][q*40+2s+1]) ; nKt2[s] = transposed slice.
    // 20+20 half2 = 40 VGPRs (vs 80 fp32) -> fits 2 blocks/CU without spill.
    const int r = (tid >> 2) < N ? (tid >> 2) : (N - 1);   // clamped for uniform exec
    const int q = tid & 3;
    const bool writer = (q == 0) && ((tid >> 2) < N);
    const bool act = (tid >> 2) < N;

    __half2 nKu2[QUART / 2];
    __half2 nKt2[QUART / 2];
    {
        const float xe = xeta[r], xp = xphi[r];   // row r of x
        const float ye = yeta[r], yp = yphi[r];   // col r of y
        #pragma unroll
        for (int s = 0; s < QUART / 2; ++s) {
            const int j0 = q * QUART + 2 * s;
            float ku0 = PADK, ku1 = PADK, kt0 = PADK, kt1 = PADK;
            if (j0 < N) {
                float de = xe - yeta[j0], dp = xp - yphi[j0];
                ku0 = -sqrtf(de * de + dp * dp + EPS_F) * INV_EPSLN2;
                de = xeta[j0] - ye; dp = xphi[j0] - yp;
                kt0 = -sqrtf(de * de + dp * dp + EPS_F) * INV_EPSLN2;
            }
            if (j0 + 1 < N) {
                float de = xe - yeta[j0 + 1], dp = xp - yphi[j0 + 1];
                ku1 = -sqrtf(de * de + dp * dp + EPS_F) * INV_EPSLN2;
                de = xeta[j0 + 1] - ye; dp = xphi[j0 + 1] - yp;
                kt1 = -sqrtf(de * de + dp * dp + EPS_F) * INV_EPSLN2;
            }
            nKu2[s] = __floats2half2_rn(ku0, ku1);
            nKt2[s] = __floats2half2_rn(kt0, kt1);
        }
    }
    const float la = l2a[r];
    const float lb = l2b[r];
    if (tid < NP) {
        const float z = (tid < N) ? 0.f : NEGBIG;   // pads stay NEGBIG forever
        uu[tid] = z; vv[tid] = z;
    }
    __syncthreads();

    // ---- warm-up: two-pass LSE, establish per-row/col maxes ----
    float mu = 0.f, mv = 0.f;
    for (int it = 0; it < WARM; ++it) {
        {   // u-pass
            const float4* vp = (const float4*)&vv[q * QUART];
            float mx = -3e38f;
            #pragma unroll
            for (int s = 0; s < QUADS; ++s) {
                const float4 v4 = vp[s];
                const float2 a = __half22float2(nKu2[2 * s]);
                const float2 c2 = __half22float2(nKu2[2 * s + 1]);
                mx = fmaxf(mx, fmaxf(fmaxf(v4.x + a.x, v4.y + a.y),
                                     fmaxf(v4.z + c2.x, v4.w + c2.y)));
            }
            mx = quad_max(mx);
            mu = mx;
            float s0 = 0.f, s1 = 0.f;
            #pragma unroll
            for (int s = 0; s < QUADS; ++s) {
                const float4 v4 = vp[s];
                const float2 a = __half22float2(nKu2[2 * s]);
                const float2 c2 = __half22float2(nKu2[2 * s + 1]);
                s0 += FEXP2(v4.x + a.x - mx);
                s1 += FEXP2(v4.y + a.y - mx);
                s0 += FEXP2(v4.z + c2.x - mx);
                s1 += FEXP2(v4.w + c2.y - mx);
            }
            float ss = quad_sum(s0 + s1);
            if (writer) uu[r] = la - (mx + FLOG2(fmaxf(ss, 1e-37f)));
        }
        __syncthreads();
        {   // v-pass
            const float4* up = (const float4*)&uu[q * QUART];
            float mx = -3e38f;
            #pragma unroll
            for (int s = 0; s < QUADS; ++s) {
                const float4 u4 = up[s];
                const float2 a = __half22float2(nKt2[2 * s]);
                const float2 c2 = __half22float2(nKt2[2 * s + 1]);
                mx = fmaxf(mx, fmaxf(fmaxf(u4.x + a.x, u4.y + a.y),
                                     fmaxf(u4.z + c2.x, u4.w + c2.y)));
            }
            mx = quad_max(mx);
            mv = mx;
            float s0 = 0.f, s1 = 0.f;
            #pragma unroll
            for (int s = 0; s < QUADS; ++s) {
                const float4 u4 = up[s];
                const float2 a = __half22float2(nKt2[2 * s]);
                const float2 c2 = __half22float2(nKt2[2 * s + 1]);
                s0 += FEXP2(u4.x + a.x - mx);
                s1 += FEXP2(u4.y + a.y - mx);
                s0 += FEXP2(u4.z + c2.x - mx);
                s1 += FEXP2(u4.w + c2.y - mx);
            }
            float ss = quad_sum(s0 + s1);
            if (writer) vv[r] = lb - (mx + FLOG2(fmaxf(ss, 1e-37f)));
        }
        __syncthreads();
    }

    // ---- steady state: single-pass LSE with frozen fp32 offsets mu/mv ----
    for (int it = WARM; it < ITERS; ++it) {
        {   // u-pass: t = (v - mu) + k
            const float4* vp = (const float4*)&vv[q * QUART];
            float s0 = 0.f, s1 = 0.f;
            #pragma unroll
            for (int s = 0; s < QUADS; ++s) {
                const float4 v4 = vp[s];
                const float2 a = __half22float2(nKu2[2 * s]);
                const float2 c2 = __half22float2(nKu2[2 * s + 1]);
                s0 += FEXP2(fminf((v4.x - mu) + a.x, 100.f));
                s1 += FEXP2(fminf((v4.y - mu) + a.y, 100.f));
                s0 += FEXP2(fminf((v4.z - mu) + c2.x, 100.f));
                s1 += FEXP2(fminf((v4.w - mu) + c2.y, 100.f));
            }
            float ss = quad_sum(s0 + s1);
            if (writer) uu[r] = la - (mu + FLOG2(fmaxf(ss, 1e-37f)));
        }
        __syncthreads();
        {   // v-pass
            const float4* up = (const float4*)&uu[q * QUART];
            float s0 = 0.f, s1 = 0.f;
            #pragma unroll
            for (int s = 0; s < QUADS; ++s) {
                const float4 u4 = up[s];
                const float2 a = __half22float2(nKt2[2 * s]);
                const float2 c2 = __half22float2(nKt2[2 * s + 1]);
                s0 += FEXP2(fminf((u4.x - mv) + a.x, 100.f));
                s1 += FEXP2(fminf((u4.y - mv) + a.y, 100.f));
                s0 += FEXP2(fminf((u4.z - mv) + c2.x, 100.f));
                s1 += FEXP2(fminf((u4.w - mv) + c2.y, 100.f));
            }
            float ss = quad_sum(s0 + s1);
            if (writer) vv[r] = lb - (mv + FLOG2(fmaxf(ss, 1e-37f)));
        }
        __syncthreads();
    }

    // ---- EMD = eps*ln2 * sum exp2(u+v-K)*K ;  k == -K ----
    float acc = 0.f;
    {
        const float ur = uu[r];
        const float4* vp = (const float4*)&vv[q * QUART];
        #pragma unroll
        for (int s = 0; s < QUADS; ++s) {
            const float4 v4 = vp[s];
            const float2 a = __half22float2(nKu2[2 * s]);
            const float2 c2 = __half22float2(nKu2[2 * s + 1]);
            acc += FEXP2(fminf(ur + v4.x + a.x, 100.f)) * (-a.x);
            acc += FEXP2(fminf(ur + v4.y + a.y, 100.f)) * (-a.y);
            acc += FEXP2(fminf(ur + v4.z + c2.x, 100.f)) * (-c2.x);
            acc += FEXP2(fminf(ur + v4.w + c2.y, 100.f)) * (-c2.y);
        }
    }
    if (!act) acc = 0.f;    // clamped-r threads would duplicate row 149
    acc = blockReduceSum(acc, red);
    if (tid == 0) atomicAdd(out, acc * EPSLN2);
}

extern "C" void kernel_launch(void* const* d_in, const int* in_sizes, int n_in,
                              void* d_out, int out_size, void* d_ws, size_t ws_size,
                              hipStream_t stream) {
    const float* pr = (const float*)d_in[0];
    const float* pt = (const float*)d_in[1];
    float* out = (float*)d_out;
    const int B = in_sizes[0] / (N * 3);
    (void)hipMemsetAsync(d_out, 0, sizeof(float) * out_size, stream);
    hipLaunchKernelGGL(emd_kernel, dim3(B), dim3(BLOCK), 0, stream, pr, pt, out);
}

// Round 9
// 2399.048 us; speedup vs baseline: 2.8679x; 2.8679x over previous
//
#include <hip/hip_runtime.h>
#include <hip/hip_fp16.h>
#include <math.h>

#define N 150
#define NP 160            // padded: 4 workers × 40 cols, float4-aligned
#define QUART 40
#define QUADS 10          // QUART/4
#define BLOCK 640         // 10 waves; 4 workers per row (600 active)
#define ITERS 100
#define WARM 5

#define PI_F 3.14159265358979323846f
#define TWO_PI_F 6.28318530717958647692f
#define EPS_F 1e-16f
// SINKHORN_EPS = 0.05 ; base-2 log domain: K = C/(eps*ln2), result scale eps*ln2
#define EPSLN2 0.03465735902799726f
#define INV_EPSLN2 28.853900817779268f
#define NEGBIG -1e30f
#define PADK -60000.0f    // fp16-finite pad: exp2 -> 0, K*0 -> 0 (no inf*0 NaN)

#if __has_builtin(__builtin_amdgcn_exp2f)
#define FEXP2(x) __builtin_amdgcn_exp2f(x)
#else
#define FEXP2(x) exp2f(x)
#endif
#if __has_builtin(__builtin_amdgcn_logf)
#define FLOG2(x) __builtin_amdgcn_logf(x)
#else
#define FLOG2(x) log2f(x)
#endif

// DPP quad_perm cross-lane (workers of one row are a lane-quad): pure VALU.
template <int PAT>
__device__ __forceinline__ float qp_swap(float v) {
    return __int_as_float(__builtin_amdgcn_update_dpp(
        0, __float_as_int(v), PAT, 0xF, 0xF, true));
}
__device__ __forceinline__ float quad_sum(float v) {
    v += qp_swap<0xB1>(v);   // xor 1
    v += qp_swap<0x4E>(v);   // xor 2
    return v;
}
__device__ __forceinline__ float quad_max(float v) {
    v = fmaxf(v, qp_swap<0xB1>(v));
    v = fmaxf(v, qp_swap<0x4E>(v));
    return v;
}

__device__ __forceinline__ float blockReduceSum(float v, float* red) {
    for (int o = 32; o > 0; o >>= 1) v += __shfl_down(v, o, 64);
    const int lane = threadIdx.x & 63;
    const int wv = threadIdx.x >> 6;
    __syncthreads();
    if (lane == 0) red[wv] = v;
    __syncthreads();
    float s = 0.f;
    #pragma unroll
    for (int i = 0; i < BLOCK / 64; ++i) s += red[i];
    return s;
}

// Relaxed bound: tight caps make the allocator dump indexed arrays to scratch
// (R3/R4/R7/R8). Demand is ~56-70 with fp16-packed K; allocator lands there
// naturally and 2 blocks/CU become resident by arithmetic, not by decree.
__global__ __launch_bounds__(BLOCK, 2) void emd_kernel(
    const float* __restrict__ p_recons,
    const float* __restrict__ p_target,
    float* __restrict__ out)
{
    __shared__ float xeta[N], xphi[N], yeta[N], yphi[N];
    __shared__ float l2a[N], l2b[N];
    __shared__ __align__(16) float uu[NP];
    __shared__ __align__(16) float vv[NP];
    __shared__ float red[BLOCK / 64];

    const int b = blockIdx.x;
    const int tid = threadIdx.x;

    // ---- coordinate transform (both clouds) ----
    for (int c = 0; c < 2; ++c) {
        const float* P = (c == 0 ? p_recons : p_target) + (size_t)b * (N * 3);
        float px = 0.f, py = 0.f, pz = 0.f;
        if (tid < N) {
            px = P[tid * 3 + 0];
            py = P[tid * 3 + 1];
            pz = P[tid * 3 + 2];
        }
        const float jx = blockReduceSum(px, red);
        const float jy = blockReduceSum(py, red);
        const float jz = blockReduceSum(pz, red);
        const float jpt  = sqrtf(jx * jx + jy * jy + EPS_F);
        const float jphi = atan2f(jy + EPS_F, jx + EPS_F);
        const float jeta = asinhf(jz / (jpt + EPS_F));

        float ptrel = 0.f, erel = 0.f, prel = 0.f;
        if (tid < N) {
            const float pt  = sqrtf(px * px + py * py + EPS_F);
            const float phi = atan2f(py + EPS_F, px + EPS_F);
            const float eta = asinhf(pz / (pt + EPS_F));
            erel = eta - jeta;
            float d = phi - jphi + PI_F;
            d = fmodf(d, TWO_PI_F);            // JAX % is floor-mod
            if (d < 0.f) d += TWO_PI_F;
            prel = d - PI_F;
            ptrel = pt / (jpt + EPS_F);
        }
        const float spt = blockReduceSum(ptrel, red);
        if (tid < N) {
            const float aa = ptrel / (spt + EPS_F);
            if (c == 0) { xeta[tid] = erel; xphi[tid] = prel; l2a[tid] = FLOG2(aa + EPS_F); }
            else        { yeta[tid] = erel; yphi[tid] = prel; l2b[tid] = FLOG2(aa + EPS_F); }
        }
    }
    __syncthreads();

    // ---- register-resident PACKED fp16 -K slices: 4 workers/row, 40 cols each ----
    const int r = (tid >> 2) < N ? (tid >> 2) : (N - 1);   // clamped for uniform exec
    const int q = tid & 3;
    const bool writer = (q == 0) && ((tid >> 2) < N);
    const bool act = (tid >> 2) < N;

    __half2 nKu2[QUART / 2];
    __half2 nKt2[QUART / 2];
    {
        const float xe = xeta[r], xp = xphi[r];   // row r of x
        const float ye = yeta[r], yp = yphi[r];   // col r of y
        #pragma unroll
        for (int s = 0; s < QUART / 2; ++s) {
            const int j0 = q * QUART + 2 * s;
            float ku0 = PADK, ku1 = PADK, kt0 = PADK, kt1 = PADK;
            if (j0 < N) {
                float de = xe - yeta[j0], dp = xp - yphi[j0];
                ku0 = -sqrtf(de * de + dp * dp + EPS_F) * INV_EPSLN2;
                de = xeta[j0] - ye; dp = xphi[j0] - yp;
                kt0 = -sqrtf(de * de + dp * dp + EPS_F) * INV_EPSLN2;
            }
            if (j0 + 1 < N) {
                float de = xe - yeta[j0 + 1], dp = xp - yphi[j0 + 1];
                ku1 = -sqrtf(de * de + dp * dp + EPS_F) * INV_EPSLN2;
                de = xeta[j0 + 1] - ye; dp = xphi[j0 + 1] - yp;
                kt1 = -sqrtf(de * de + dp * dp + EPS_F) * INV_EPSLN2;
            }
            nKu2[s] = __floats2half2_rn(ku0, ku1);
            nKt2[s] = __floats2half2_rn(kt0, kt1);
        }
    }
    const float la = l2a[r];
    const float lb = l2b[r];
    if (tid < NP) {
        const float z = (tid < N) ? 0.f : NEGBIG;   // pads stay NEGBIG forever
        uu[tid] = z; vv[tid] = z;
    }
    __syncthreads();

    // ---- warm-up: two-pass LSE, establish per-row/col maxes ----
    float mu = 0.f, mv = 0.f;
    for (int it = 0; it < WARM; ++it) {
        {   // u-pass
            const float4* vp = (const float4*)&vv[q * QUART];
            float mx = -3e38f;
            #pragma unroll
            for (int s = 0; s < QUADS; ++s) {
                const float4 v4 = vp[s];
                const float2 a = __half22float2(nKu2[2 * s]);
                const float2 c2 = __half22float2(nKu2[2 * s + 1]);
                mx = fmaxf(mx, fmaxf(fmaxf(v4.x + a.x, v4.y + a.y),
                                     fmaxf(v4.z + c2.x, v4.w + c2.y)));
            }
            mx = quad_max(mx);
            mu = mx;
            float s0 = 0.f, s1 = 0.f;
            #pragma unroll
            for (int s = 0; s < QUADS; ++s) {
                const float4 v4 = vp[s];
                const float2 a = __half22float2(nKu2[2 * s]);
                const float2 c2 = __half22float2(nKu2[2 * s + 1]);
                s0 += FEXP2(v4.x + a.x - mx);
                s1 += FEXP2(v4.y + a.y - mx);
                s0 += FEXP2(v4.z + c2.x - mx);
                s1 += FEXP2(v4.w + c2.y - mx);
            }
            float ss = quad_sum(s0 + s1);
            if (writer) uu[r] = la - (mx + FLOG2(fmaxf(ss, 1e-37f)));
        }
        __syncthreads();
        {   // v-pass
            const float4* up = (const float4*)&uu[q * QUART];
            float mx = -3e38f;
            #pragma unroll
            for (int s = 0; s < QUADS; ++s) {
                const float4 u4 = up[s];
                const float2 a = __half22float2(nKt2[2 * s]);
                const float2 c2 = __half22float2(nKt2[2 * s + 1]);
                mx = fmaxf(mx, fmaxf(fmaxf(u4.x + a.x, u4.y + a.y),
                                     fmaxf(u4.z + c2.x, u4.w + c2.y)));
            }
            mx = quad_max(mx);
            mv = mx;
            float s0 = 0.f, s1 = 0.f;
            #pragma unroll
            for (int s = 0; s < QUADS; ++s) {
                const float4 u4 = up[s];
                const float2 a = __half22float2(nKt2[2 * s]);
                const float2 c2 = __half22float2(nKt2[2 * s + 1]);
                s0 += FEXP2(u4.x + a.x - mx);
                s1 += FEXP2(u4.y + a.y - mx);
                s0 += FEXP2(u4.z + c2.x - mx);
                s1 += FEXP2(u4.w + c2.y - mx);
            }
            float ss = quad_sum(s0 + s1);
            if (writer) vv[r] = lb - (mx + FLOG2(fmaxf(ss, 1e-37f)));
        }
        __syncthreads();
    }

    // ---- steady state: single-pass LSE with frozen fp32 offsets mu/mv ----
    for (int it = WARM; it < ITERS; ++it) {
        {   // u-pass: t = (v - mu) + k
            const float4* vp = (const float4*)&vv[q * QUART];
            float s0 = 0.f, s1 = 0.f;
            #pragma unroll
            for (int s = 0; s < QUADS; ++s) {
                const float4 v4 = vp[s];
                const float2 a = __half22float2(nKu2[2 * s]);
                const float2 c2 = __half22float2(nKu2[2 * s + 1]);
                s0 += FEXP2(fminf((v4.x - mu) + a.x, 100.f));
                s1 += FEXP2(fminf((v4.y - mu) + a.y, 100.f));
                s0 += FEXP2(fminf((v4.z - mu) + c2.x, 100.f));
                s1 += FEXP2(fminf((v4.w - mu) + c2.y, 100.f));
            }
            float ss = quad_sum(s0 + s1);
            if (writer) uu[r] = la - (mu + FLOG2(fmaxf(ss, 1e-37f)));
        }
        __syncthreads();
        {   // v-pass
            const float4* up = (const float4*)&uu[q * QUART];
            float s0 = 0.f, s1 = 0.f;
            #pragma unroll
            for (int s = 0; s < QUADS; ++s) {
                const float4 u4 = up[s];
                const float2 a = __half22float2(nKt2[2 * s]);
                const float2 c2 = __half22float2(nKt2[2 * s + 1]);
                s0 += FEXP2(fminf((u4.x - mv) + a.x, 100.f));
                s1 += FEXP2(fminf((u4.y - mv) + a.y, 100.f));
                s0 += FEXP2(fminf((u4.z - mv) + c2.x, 100.f));
                s1 += FEXP2(fminf((u4.w - mv) + c2.y, 100.f));
            }
            float ss = quad_sum(s0 + s1);
            if (writer) vv[r] = lb - (mv + FLOG2(fmaxf(ss, 1e-37f)));
        }
        __syncthreads();
    }

    // ---- EMD = eps*ln2 * sum exp2(u+v-K)*K ;  k == -K ----
    float acc = 0.f;
    {
        const float ur = uu[r];
        const float4* vp = (const float4*)&vv[q * QUART];
        #pragma unroll
        for (int s = 0; s < QUADS; ++s) {
            const float4 v4 = vp[s];
            const float2 a = __half22float2(nKu2[2 * s]);
            const float2 c2 = __half22float2(nKu2[2 * s + 1]);
            acc += FEXP2(fminf(ur + v4.x + a.x, 100.f)) * (-a.x);
            acc += FEXP2(fminf(ur + v4.y + a.y, 100.f)) * (-a.y);
            acc += FEXP2(fminf(ur + v4.z + c2.x, 100.f)) * (-c2.x);
            acc += FEXP2(fminf(ur + v4.w + c2.y, 100.f)) * (-c2.y);
        }
    }
    if (!act) acc = 0.f;    // clamped-r threads would duplicate row 149
    acc = blockReduceSum(acc, red);
    if (tid == 0) atomicAdd(out, acc * EPSLN2);
}

extern "C" void kernel_launch(void* const* d_in, const int* in_sizes, int n_in,
                              void* d_out, int out_size, void* d_ws, size_t ws_size,
                              hipStream_t stream) {
    const float* pr = (const float*)d_in[0];
    const float* pt = (const float*)d_in[1];
    float* out = (float*)d_out;
    const int B = in_sizes[0] / (N * 3);
    (void)hipMemsetAsync(d_out, 0, sizeof(float) * out_size, stream);
    hipLaunchKernelGGL(emd_kernel, dim3(B), dim3(BLOCK), 0, stream, pr, pt, out);
}